// Round 1
// baseline (543.020 us; speedup 1.0000x reference)
//
#include <hip/hip_runtime.h>

// SNN elementwise state update. Memory-bound: 5 reads + 5 writes of 64 MiB fp32.
// CFG: dt=0.5, kappa_j=0.2, tau_j=8.0, gamma_m=0.1, R_m=5.0, tau_m=10.0,
//      thresh=1.0, t_ref=2.0, tau_tr=20.0

__device__ __forceinline__ void snn_step(float I, float v, float x, float j, float r,
                                         float& vo, float& so, float& xo,
                                         float& jo, float& ro) {
#pragma clang fp contract(off)
    // refractory countdown
    float rc = fmaxf(r - 0.5f, 0.0f);
    // synaptic current: j += (dt/tau_j) * (-kappa_j*j + I); dt/tau_j = 0.0625 exact
    float jn = j + 0.0625f * (-0.2f * j + I);
    // membrane potential, frozen while refractory
    float isr = (rc > 0.0f) ? 1.0f : 0.0f;
    float vn = v + ((1.0f - isr) * 0.05f) * ((-0.1f) * v + 5.0f * jn);
    // threshold -> spike, reset
    float sp = (vn > 1.0f) ? 1.0f : 0.0f;
    vo = vn * (1.0f - sp);
    so = sp;
    // low-pass spike trace: x - x/tau_tr + spikes (true division to match ref rounding)
    xo = x - x / 20.0f + sp;
    jo = jn;
    ro = (sp > 0.0f) ? 2.0f : rc;
}

__global__ __launch_bounds__(256) void bPC_SNNLayer_65274912965275_kernel(
    const float4* __restrict__ Ic,
    const float4* __restrict__ v_in,
    const float4* __restrict__ x_in,
    const float4* __restrict__ j_in,
    const float4* __restrict__ r_in,
    float4* __restrict__ v_out,
    float4* __restrict__ s_out,
    float4* __restrict__ x_out,
    float4* __restrict__ j_out,
    float4* __restrict__ r_out,
    int n4) {
#pragma clang fp contract(off)
    int idx = blockIdx.x * blockDim.x + threadIdx.x;
    if (idx >= n4) return;

    float4 I = Ic[idx];
    float4 v = v_in[idx];
    float4 x = x_in[idx];
    float4 j = j_in[idx];
    float4 r = r_in[idx];

    float4 vo, so, xo, jo, ro;
    snn_step(I.x, v.x, x.x, j.x, r.x, vo.x, so.x, xo.x, jo.x, ro.x);
    snn_step(I.y, v.y, x.y, j.y, r.y, vo.y, so.y, xo.y, jo.y, ro.y);
    snn_step(I.z, v.z, x.z, j.z, r.z, vo.z, so.z, xo.z, jo.z, ro.z);
    snn_step(I.w, v.w, x.w, j.w, r.w, vo.w, so.w, xo.w, jo.w, ro.w);

    v_out[idx] = vo;
    s_out[idx] = so;
    x_out[idx] = xo;
    j_out[idx] = jo;
    r_out[idx] = ro;
}

extern "C" void kernel_launch(void* const* d_in, const int* in_sizes, int n_in,
                              void* d_out, int out_size, void* d_ws, size_t ws_size,
                              hipStream_t stream) {
    // setup_inputs order: total_input_current, v, x, j, ref_count
    const float* I = (const float*)d_in[0];
    const float* v = (const float*)d_in[1];
    const float* x = (const float*)d_in[2];
    const float* j = (const float*)d_in[3];
    const float* r = (const float*)d_in[4];

    const int n = in_sizes[0];       // 4096*4096 = 16777216, divisible by 4
    const int n4 = n / 4;

    float* out = (float*)d_out;      // (v, s, x, j, ref_count) concatenated
    float* vo = out;
    float* so = out + (size_t)n;
    float* xo = out + 2 * (size_t)n;
    float* jo = out + 3 * (size_t)n;
    float* ro = out + 4 * (size_t)n;

    const int block = 256;
    const int grid = (n4 + block - 1) / block;  // 16384 blocks
    bPC_SNNLayer_65274912965275_kernel<<<grid, block, 0, stream>>>(
        (const float4*)I, (const float4*)v, (const float4*)x,
        (const float4*)j, (const float4*)r,
        (float4*)vo, (float4*)so, (float4*)xo, (float4*)jo, (float4*)ro, n4);
}